// Round 6
// baseline (1302.690 us; speedup 1.0000x reference)
//
#include <hip/hip_runtime.h>
#include <math.h>

typedef unsigned short u16;
typedef __attribute__((ext_vector_type(8))) short bfrag;   // 8 bf16 (4 VGPRs)
typedef __attribute__((ext_vector_type(4))) float f32x4;

__device__ __forceinline__ float gelu_f(float x){
  return 0.5f * x * (1.0f + erff(x * 0.70710678118654752440f));
}
__device__ __forceinline__ u16 f2bf(float f){
  union { float f; unsigned int i; } c; c.f = f;
  unsigned int i = c.i;
  return (u16)((i + 0x7FFFu + ((i >> 16) & 1u)) >> 16);
}
__device__ __forceinline__ float bf2f(u16 u){
  union { unsigned int i; float f; } c; c.i = ((unsigned int)u) << 16; return c.f;
}

struct F8 { float v[8]; };
__device__ __forceinline__ F8 load8f(const float* p){
  float4 a = *(const float4*)p; float4 b = *(const float4*)(p + 4);
  F8 r; r.v[0]=a.x; r.v[1]=a.y; r.v[2]=a.z; r.v[3]=a.w;
  r.v[4]=b.x; r.v[5]=b.y; r.v[6]=b.z; r.v[7]=b.w; return r;
}

// async global->LDS, 16B per lane; LDS dest = wave-uniform base + lane*16
__device__ __forceinline__ void async16(const void* g, void* l){
  __builtin_amdgcn_global_load_lds(
      (const __attribute__((address_space(1))) unsigned int*)g,
      (__attribute__((address_space(3))) unsigned int*)l, 16, 0, 0);
}

#define PRE_STRIDE 4624

// ============ k0 phase A: mlp_s (2->256->2) + residual -> GT1 ==============
__global__ __launch_bounds__(256) void k0a_mlps(
    const float* __restrict__ gtok,
    const float* __restrict__ ws1_w, const float* __restrict__ ws1_b,
    const float* __restrict__ ws2_w, const float* __restrict__ ws2_b,
    float* __restrict__ GT1)
{
  __shared__ float sw1[256][2]; __shared__ float sb1[256];
  __shared__ float sw2[2][256];
  const int b = blockIdx.x;
  const int t = threadIdx.x;
  sw1[t][0] = ws1_w[2*t]; sw1[t][1] = ws1_w[2*t+1];
  sb1[t] = ws1_b[t];
  sw2[0][t] = ws2_w[t]; sw2[1][t] = ws2_w[256+t];
  __syncthreads();
  const int j = blockIdx.y*256 + t;
  const float a0 = gtok[b*1024 + 2*j], a1 = gtok[b*1024 + 2*j + 1];
  float s0 = ws2_b[0], s1 = ws2_b[1];
  #pragma unroll 4
  for (int o = 0; o < 256; ++o){
    float h = gelu_f(sw1[o][0]*a0 + sw1[o][1]*a1 + sb1[o]);
    s0 += sw2[0][o]*h; s1 += sw2[1][o]*h;
  }
  GT1[b*1024 + 2*j]     = a0 + s0;
  GT1[b*1024 + 2*j + 1] = a1 + s1;
}

// ============ k0 phase B: fc1 of mlp_c (512->2048) -> HID ==================
__global__ __launch_bounds__(256) void k0b_fc1(
    const float* __restrict__ GT1,
    const float* __restrict__ wc1_w, const float* __restrict__ wc1_b,
    float* __restrict__ HID)
{
  __shared__ float g[1024];
  const int b = blockIdx.x;
  const int t = threadIdx.x;
  for (int i = t; i < 1024; i += 256) g[i] = GT1[b*1024 + i];
  __syncthreads();
  const int o = blockIdx.y*256 + t;
  const float* wr = wc1_w + (size_t)o*512;
  float acc0 = wc1_b[o], acc1 = acc0;
  for (int d = 0; d < 512; d += 8){
    F8 w = load8f(wr + d);
    #pragma unroll
    for (int i = 0; i < 8; ++i){
      acc0 += w.v[i]*g[(d+i)*2];
      acc1 += w.v[i]*g[(d+i)*2+1];
    }
  }
  HID[b*4096 + o]        = gelu_f(acc0);
  HID[b*4096 + 2048 + o] = gelu_f(acc1);
}

// ============ k0 phase C: fc2 of mlp_c (2048->512) + residual -> GT2 =======
__global__ __launch_bounds__(256) void k0c_fc2(
    const float* __restrict__ GT1, const float* __restrict__ HID,
    const float* __restrict__ wc2_w, const float* __restrict__ wc2_b,
    float* __restrict__ GT2)
{
  __shared__ float h0[2048], h1[2048];
  const int b = blockIdx.x;
  const int t = threadIdx.x;
  for (int i = t; i < 2048; i += 256){
    h0[i] = HID[b*4096 + i]; h1[i] = HID[b*4096 + 2048 + i];
  }
  __syncthreads();
  const int d = blockIdx.y*256 + t;
  const float* wr = wc2_w + (size_t)d*2048;
  float acc0 = wc2_b[d], acc1 = acc0;
  for (int o = 0; o < 2048; o += 8){
    F8 w = load8f(wr + o);
    #pragma unroll
    for (int i = 0; i < 8; ++i){
      acc0 += w.v[i]*h0[o+i];
      acc1 += w.v[i]*h1[o+i];
    }
  }
  GT2[b*1024 + 2*d]     = GT1[b*1024 + 2*d]     + acc0;
  GT2[b*1024 + 2*d + 1] = GT1[b*1024 + 2*d + 1] + acc1;
}

// ============ k0 phase D: k,v -> dk, dv, v1l ================================
__global__ __launch_bounds__(256) void k0d_kv(
    const float* __restrict__ GT2,
    const float* __restrict__ k_w,
    const float* __restrict__ v_w, const float* __restrict__ v_b,
    float* __restrict__ DK, float* __restrict__ DV, float* __restrict__ V1L)
{
  __shared__ float g[1024];
  const int b = blockIdx.x;
  const int t = threadIdx.x;
  for (int i = t; i < 1024; i += 256) g[i] = GT2[b*1024 + i];
  __syncthreads();
  const int c = blockIdx.y*256 + t;
  const float* kr = k_w + (size_t)c*512;
  const float* vr = v_w + (size_t)c*512;
  float k0a=0.f,k1a=0.f,v0a=0.f,v1a=0.f;
  for (int d = 0; d < 512; d += 8){
    F8 kw = load8f(kr + d); F8 vw = load8f(vr + d);
    #pragma unroll
    for (int i = 0; i < 8; ++i){
      float g0 = g[(d+i)*2], g1 = g[(d+i)*2+1];
      k0a += kw.v[i]*g0; k1a += kw.v[i]*g1;
      v0a += vw.v[i]*g0; v1a += vw.v[i]*g1;
    }
  }
  DK[b*512 + c]  = k0a - k1a;
  DV[b*512 + c]  = v0a - v1a;
  V1L[b*512 + c] = v1a + v_b[c];
}

// ============ k0 phase E: wdiff + beta4 -> PRE ==============================
__global__ __launch_bounds__(256) void k0e_qpre(
    const float* __restrict__ DK,
    const float* __restrict__ q_w, const float* __restrict__ q_b,
    float* __restrict__ PRE)
{
  __shared__ float dkl[512];
  const int b = blockIdx.x;
  const int t = threadIdx.x;
  for (int i = t; i < 512; i += 256) dkl[i] = DK[b*512 + i];
  __syncthreads();
  const int i = blockIdx.y*256 + t;
  float w0=0.f,w1=0.f,w2=0.f,w3=0.f;
  for (int c = 0; c < 512; c += 4){
    w0 += dkl[c]  *q_w[(size_t)(c)  *512 + i];
    w1 += dkl[c+1]*q_w[(size_t)(c+1)*512 + i];
    w2 += dkl[c+2]*q_w[(size_t)(c+2)*512 + i];
    w3 += dkl[c+3]*q_w[(size_t)(c+3)*512 + i];
  }
  float* P = PRE + (size_t)b * PRE_STRIDE;
  P[0*512+i]=w0; P[1*512+i]=w1; P[2*512+i]=w2; P[3*512+i]=w3;
  if (blockIdx.y == 0 && t < 4){
    float bsum = 0.f;
    for (int c = t; c < 512; c += 4) bsum += dkl[c]*q_b[c];
    P[2048 + t] = bsum;
  }
}

// ============ k0 phase F: base + M -> PRE ===================================
__global__ __launch_bounds__(256) void k0f_mpre(
    const float* __restrict__ DV, const float* __restrict__ V1L,
    const float* __restrict__ merge_w, const float* __restrict__ merge_b,
    float* __restrict__ PRE)
{
  __shared__ float dvl[512], v1ll[512];
  const int b = blockIdx.x;
  const int t = threadIdx.x;
  for (int i = t; i < 512; i += 256){
    dvl[i] = DV[b*512 + i]; v1ll[i] = V1L[b*512 + i];
  }
  __syncthreads();
  const int r = blockIdx.y*256 + t;
  const float* mw = merge_w + (size_t)r*512;
  float ab = merge_b[r];
  float mh[4] = {0.f,0.f,0.f,0.f};
  for (int c = 0; c < 512; c += 8){
    F8 w = load8f(mw + c);
    #pragma unroll
    for (int i = 0; i < 8; ++i){
      ab += w.v[i]*v1ll[c+i];
      mh[i&3] += w.v[i]*dvl[c+i];
    }
  }
  float* P = PRE + (size_t)b * PRE_STRIDE;
  P[2064 + r] = ab;
  *(float4*)&P[2576 + r*4] = make_float4(mh[0],mh[1],mh[2],mh[3]);
}

// ---------------- convert fp32 -> bf16 (flat) ------------------------------
__global__ __launch_bounds__(256) void kcvt(const float* __restrict__ s,
                                            u16* __restrict__ d, int n8)
{
  int g = blockIdx.x*256 + threadIdx.x;
  if (g >= n8) return;
  F8 v = load8f(s + (size_t)g*8);
  u16 o[8];
  #pragma unroll
  for (int i=0;i<8;++i) o[i] = f2bf(v.v[i]);
  *(uint4*)(d + (size_t)g*8) = *(uint4*)o;
}

// ------- build Wg64 [64][1024] = [g1_w | g1_w] bf16 ------------------------
__global__ __launch_bounds__(256) void kcvt_dup(const float* __restrict__ g1w,
                                                u16* __restrict__ out)
{
  int idx = blockIdx.x*256 + threadIdx.x;      // 65536 total
  int r = idx >> 10, k = idx & 1023;
  out[idx] = f2bf(g1w[r*512 + (k & 511)]);
}

// ---- K1: one pass over x: XYbT[j][0..511]=x bf16, [512..1023]=attn+LN(n0) --
__global__ __launch_bounds__(256) void k1_fused(
    const float* __restrict__ x, const float* __restrict__ PRE,
    const float* __restrict__ n0_g, const float* __restrict__ n0_b,
    int j0_global, u16* __restrict__ XYbT)
{
  __shared__ float wd[4][512];
  __shared__ float bs[512];
  __shared__ float Mm[512][4];
  __shared__ float gam[512], bet[512];
  __shared__ float beta4[4];
  const int tid = threadIdx.x;
  const int jl = blockIdx.x*256 + tid;
  const int jg = j0_global + jl;
  const int b = jg >> 12, n = jg & 4095;
  const float* P = PRE + (size_t)b * PRE_STRIDE;
  for (int i = tid; i < 2048; i += 256) wd[i>>9][i&511] = P[i];
  if (tid < 4) beta4[tid] = P[2048 + tid];
  for (int i = tid; i < 512; i += 256){
    bs[i] = P[2064 + i]; gam[i] = n0_g[i]; bet[i] = n0_b[i];
  }
  for (int i = tid; i < 2048; i += 256) Mm[i>>2][i&3] = P[2576 + i];
  __syncthreads();
  const float* xc = x + (size_t)b*2097152 + n;
  u16* col = XYbT + (size_t)jl*1024;
  float l0=beta4[0], l1=beta4[1], l2=beta4[2], l3=beta4[3];
  for (int i0 = 0; i0 < 512; i0 += 8){
    u16 ob[8];
    #pragma unroll
    for (int m = 0; m < 8; ++m){
      float xv = xc[(size_t)(i0+m)*4096];
      ob[m] = f2bf(xv);
      l0 += wd[0][i0+m]*xv; l1 += wd[1][i0+m]*xv;
      l2 += wd[2][i0+m]*xv; l3 += wd[3][i0+m]*xv;
    }
    *(uint4*)&col[i0] = *(uint4*)ob;
  }
  const float sc = 0.0883883476483184405f;
  float p0 = 1.f/(1.f+expf(-sc*l0));
  float p1 = 1.f/(1.f+expf(-sc*l1));
  float p2 = 1.f/(1.f+expf(-sc*l2));
  float p3 = 1.f/(1.f+expf(-sc*l3));
  float s=0.f, s2=0.f;
  for (int c = 0; c < 512; ++c){
    float m = bs[c] + Mm[c][0]*p0 + Mm[c][1]*p1 + Mm[c][2]*p2 + Mm[c][3]*p3;
    s += m; s2 += m*m;
  }
  float mean = s*(1.f/512.f);
  float rs = rsqrtf(s2*(1.f/512.f) - mean*mean + 1e-5f);
  for (int c0 = 0; c0 < 512; c0 += 8){
    u16 ob[8];
    #pragma unroll
    for (int m = 0; m < 8; ++m){
      int c = c0 + m;
      float v = bs[c] + Mm[c][0]*p0 + Mm[c][1]*p1 + Mm[c][2]*p2 + Mm[c][3]*p3;
      ob[m] = f2bf((v - mean)*rs*gam[c] + bet[c]);
    }
    *(uint4*)&col[512 + c0] = *(uint4*)ob;
  }
}

// --------- MFMA GEMM: Out[C][M] bf16 = act(Wb @ XT^T + bias) ---------------
// Wb [M][K] bf16; XT [C][1024] bf16 (k-contiguous cols). 128x128 tile, BK=32.
// 1-D grid with XCD-aware swizzle: blocks sharing an X panel (same bj) get
// ids == same (mod 8) AND temporally adjacent -> one L2 fetch per panel.
// Epilogue: LDS-transposed tile (pad stride 136) -> coalesced 16B stores.
__global__ __launch_bounds__(256) void mfma_gemm_t(
    const u16* __restrict__ Wb, const float* __restrict__ bias,
    const u16* __restrict__ XT, int K, int M,
    u16* __restrict__ Out, int do_gelu, int log2nbi)
{
  __shared__ __align__(16) u16 As[128*32];
  __shared__ __align__(16) u16 Bs[128*32];
  __shared__ __align__(16) u16 Tt[64*136];
  const int tid = threadIdx.x;
  const int lane = tid & 63;
  const int wv = __builtin_amdgcn_readfirstlane(tid >> 6);
  const int id = blockIdx.x;
  const int bi = (id >> 3) & ((1 << log2nbi) - 1);
  const int bj = (id & 7) + 8 * (id >> (3 + log2nbi));
  const int roff = (wv >> 1) * 64;
  const int noff = (wv & 1) * 64;
  const int lm = lane & 15, quad = lane >> 4;

  f32x4 acc[4][4];
  #pragma unroll
  for (int i=0;i<4;++i){
    #pragma unroll
    for (int j=0;j<4;++j) acc[i][j] = (f32x4){0.f,0.f,0.f,0.f};
  }
  const u16* aG = Wb + (size_t)(bi*128 + (tid>>2))*K + (tid&3)*8;
  const u16* bG = XT + (size_t)(bj*128 + (tid>>2))*1024 + (tid&3)*8;
  char* aL = (char*)As + wv*1024;
  char* bL = (char*)Bs + wv*1024;

  for (int k0 = 0; k0 < K; k0 += 32){
    async16(aG + k0,            aL);
    async16(aG + 64*K + k0,     aL + 4096);
    async16(bG + k0,            bL);
    async16(bG + 64*1024 + k0,  bL + 4096);
    __syncthreads();
    bfrag av[4], bv[4];
    #pragma unroll
    for (int i=0;i<4;++i)
      av[i] = *(const bfrag*)&As[(roff + 16*i + lm)*32 + quad*8];
    #pragma unroll
    for (int j=0;j<4;++j)
      bv[j] = *(const bfrag*)&Bs[(noff + 16*j + lm)*32 + quad*8];
    #pragma unroll
    for (int i=0;i<4;++i){
      #pragma unroll
      for (int j=0;j<4;++j)
        acc[i][j] = __builtin_amdgcn_mfma_f32_16x16x32_bf16(av[i], bv[j], acc[i][j], 0,0,0);
    }
    __syncthreads();
  }
  // coalesced epilogue: 2 passes of 64 cols through LDS
  #pragma unroll
  for (int p = 0; p < 2; ++p){
    if ((wv & 1) == p){
      #pragma unroll
      for (int i=0;i<4;++i){
        float4 bb = *(const float4*)&bias[bi*128 + roff + 16*i + quad*4];
        float b4[4] = {bb.x,bb.y,bb.z,bb.w};
        #pragma unroll
        for (int j=0;j<4;++j){
          int colr = 16*j + lm;     // col within 64-chunk
          #pragma unroll
          for (int s2=0;s2<2;++s2){
            float v0 = acc[i][j][2*s2]   + b4[2*s2];
            float v1 = acc[i][j][2*s2+1] + b4[2*s2+1];
            if (do_gelu){ v0 = gelu_f(v0); v1 = gelu_f(v1); }
            unsigned int dw = (unsigned int)f2bf(v0) | ((unsigned int)f2bf(v1) << 16);
            *(unsigned int*)&Tt[colr*136 + roff + 16*i + quad*4 + 2*s2] = dw;
          }
        }
      }
    }
    __syncthreads();
    {
      int c = tid >> 2, q = tid & 3;          // col 0..63, row-quarter
      u16* dst = Out + (size_t)(bj*128 + p*64 + c)*M + bi*128 + q*32;
      const u16* src = &Tt[c*136 + q*32];
      #pragma unroll
      for (int m=0;m<2;++m){
        *(uint4*)(dst + m*8)      = *(const uint4*)(src + m*8);
        *(uint4*)(dst + 16 + m*8) = *(const uint4*)(src + 16 + m*8);
      }
    }
    __syncthreads();
  }
}

// --------- MFMA GEMM 64-row (g1): Out[C][64] bf16 = Wg @ XT^T + b ----------
__global__ __launch_bounds__(256) void mfma_g64(
    const u16* __restrict__ Wg, const float* __restrict__ bias,
    const u16* __restrict__ XT, u16* __restrict__ Out)
{
  __shared__ __align__(16) u16 As[64*32];
  __shared__ __align__(16) u16 Bs[256*32];
  __shared__ __align__(16) u16 Tg[256*72];
  const int tid = threadIdx.x;
  const int lane = tid & 63;
  const int wv = __builtin_amdgcn_readfirstlane(tid >> 6);
  const int bj = blockIdx.x;
  const int lm = lane & 15, quad = lane >> 4;

  f32x4 acc[4][4];
  #pragma unroll
  for (int i=0;i<4;++i){
    #pragma unroll
    for (int j=0;j<4;++j) acc[i][j] = (f32x4){0.f,0.f,0.f,0.f};
  }
  const u16* aG = Wg + (size_t)(tid>>2)*1024 + (tid&3)*8;
  const u16* bG = XT + (size_t)(bj*256 + (tid>>2))*1024 + (tid&3)*8;
  char* aL = (char*)As + wv*1024;
  char* bL = (char*)Bs + wv*1024;

  for (int k0 = 0; k0 < 1024; k0 += 32){
    async16(aG + k0, aL);
    #pragma unroll
    for (int s = 0; s < 4; ++s)
      async16(bG + (size_t)s*64*1024 + k0, bL + s*4096);
    __syncthreads();
    bfrag av[4], bv[4];
    #pragma unroll
    for (int i=0;i<4;++i)
      av[i] = *(const bfrag*)&As[(16*i + lm)*32 + quad*8];
    #pragma unroll
    for (int j=0;j<4;++j)
      bv[j] = *(const bfrag*)&Bs[(wv*64 + 16*j + lm)*32 + quad*8];
    #pragma unroll
    for (int i=0;i<4;++i){
      #pragma unroll
      for (int j=0;j<4;++j)
        acc[i][j] = __builtin_amdgcn_mfma_f32_16x16x32_bf16(av[i], bv[j], acc[i][j], 0,0,0);
    }
    __syncthreads();
  }
  // all 4 waves stage their 64x64 tiles, then coalesced store
  #pragma unroll
  for (int i=0;i<4;++i){
    float4 bb = *(const float4*)&bias[16*i + quad*4];
    float b4[4] = {bb.x,bb.y,bb.z,bb.w};
    #pragma unroll
    for (int j=0;j<4;++j){
      int col = wv*64 + 16*j + lm;
      #pragma unroll
      for (int s2=0;s2<2;++s2){
        float v0 = acc[i][j][2*s2]   + b4[2*s2];
        float v1 = acc[i][j][2*s2+1] + b4[2*s2+1];
        unsigned int dw = (unsigned int)f2bf(v0) | ((unsigned int)f2bf(v1) << 16);
        *(unsigned int*)&Tg[col*72 + 16*i + quad*4 + 2*s2] = dw;
      }
    }
  }
  __syncthreads();
  {
    u16* dst = Out + (size_t)(bj*256 + tid)*64;
    const u16* src = &Tg[tid*72];
    #pragma unroll
    for (int m=0;m<8;++m)
      *(uint4*)(dst + m*8) = *(const uint4*)(src + m*8);
  }
}

// ---- LN over 512 ch, wave-per-column; bf16 in, bf16 out into XYbT y-half --
__global__ __launch_bounds__(256) void k_lnT(
    const u16* __restrict__ t2T,
    const float* __restrict__ gamma, const float* __restrict__ beta,
    u16* __restrict__ XYbT)
{
  __shared__ float gam[512], bet[512];
  const int tid = threadIdx.x;
  for (int c = tid; c < 512; c += 256){ gam[c]=gamma[c]; bet[c]=beta[c]; }
  __syncthreads();
  const int lane = tid & 63, wv = tid >> 6;
  const int j = blockIdx.x*4 + wv;
  uint4 w = *(const uint4*)(t2T + (size_t)j*512 + lane*8);
  const u16* wp = (const u16*)&w;
  float vv[8];
  #pragma unroll
  for (int m=0;m<8;++m) vv[m] = bf2f(wp[m]);
  float s = 0.f, s2 = 0.f;
  #pragma unroll
  for (int m=0;m<8;++m){ s += vv[m]; s2 += vv[m]*vv[m]; }
  #pragma unroll
  for (int off = 32; off; off >>= 1){
    s  += __shfl_xor(s,  off, 64);
    s2 += __shfl_xor(s2, off, 64);
  }
  float mean = s*(1.f/512.f);
  float rs = rsqrtf(s2*(1.f/512.f) - mean*mean + 1e-5f);
  u16 ob[8];
  #pragma unroll
  for (int m=0;m<8;++m){
    int c = lane*8 + m;
    ob[m] = f2bf((vv[m]-mean)*rs*gam[c] + bet[c]);
  }
  *(uint4*)&XYbT[(size_t)j*1024 + 512 + lane*8] = *(uint4*)ob;
}

// ------- head: LN64+gelu -> 16 -> 4 -> 2, softmax ch0; G is [C][64] bf16 ---
__global__ __launch_bounds__(256) void k_head(
    const u16* __restrict__ G,
    const float* __restrict__ gl1_g, const float* __restrict__ gl1_b,
    const float* __restrict__ g2_w, const float* __restrict__ g2_b,
    const float* __restrict__ gl2_g, const float* __restrict__ gl2_b,
    const float* __restrict__ g3_w, const float* __restrict__ g3_b,
    const float* __restrict__ gl3_g, const float* __restrict__ gl3_b,
    const float* __restrict__ g4_w, const float* __restrict__ g4_b, int has_g4b,
    float* __restrict__ Outp, int j0_global)
{
  __shared__ float L1g[64], L1b[64];
  __shared__ float W2[16][64], B2v[16], G2v[16], T2v[16];
  __shared__ float W3[4][16], B3v[4], G3v[4], T3v[4];
  __shared__ float W4d[4]; __shared__ float b4d;
  const int tid = threadIdx.x;
  if (tid < 64){ L1g[tid]=gl1_g[tid]; L1b[tid]=gl1_b[tid]; }
  for (int i = tid; i < 1024; i += 256) W2[i>>6][i&63] = g2_w[i];
  if (tid < 16){ B2v[tid]=g2_b[tid]; G2v[tid]=gl2_g[tid]; T2v[tid]=gl2_b[tid]; }
  if (tid < 64) W3[tid>>4][tid&15] = g3_w[tid];
  if (tid < 4){ B3v[tid]=g3_b[tid]; G3v[tid]=gl3_g[tid]; T3v[tid]=gl3_b[tid];
                W4d[tid] = g4_w[tid] - g4_w[4+tid]; }
  if (tid == 0) b4d = has_g4b ? (g4_b[0] - g4_b[1]) : 0.f;
  __syncthreads();
  const int jl = blockIdx.x*256 + tid;
  const u16* gc = G + (size_t)jl*64;
  float a1[64]; float s=0.f;
  #pragma unroll
  for (int c0=0;c0<64;c0+=8){
    uint4 w = *(const uint4*)(gc + c0);
    const u16* wp = (const u16*)&w;
    #pragma unroll
    for (int m=0;m<8;++m){ a1[c0+m] = bf2f(wp[m]); s += a1[c0+m]; }
  }
  float m = s*(1.f/64.f); float s2=0.f;
  #pragma unroll
  for (int c=0;c<64;++c){ float d=a1[c]-m; s2+=d*d; }
  float rs = rsqrtf(s2*(1.f/64.f)+1e-5f);
  #pragma unroll
  for (int c=0;c<64;++c) a1[c] = gelu_f((a1[c]-m)*rs*L1g[c]+L1b[c]);

  float a2[16]; s=0.f;
  #pragma unroll
  for (int i=0;i<16;++i){
    float acc = B2v[i];
    #pragma unroll
    for (int o=0;o<64;++o) acc += W2[i][o]*a1[o];
    a2[i]=acc; s+=acc;
  }
  m = s*(1.f/16.f); s2=0.f;
  #pragma unroll
  for (int i=0;i<16;++i){ float d=a2[i]-m; s2+=d*d; }
  rs = rsqrtf(s2*(1.f/16.f)+1e-5f);
  float a2g[16];
  #pragma unroll
  for (int i=0;i<16;++i) a2g[i] = gelu_f((a2[i]-m)*rs*G2v[i]+T2v[i]);

  float a3[4]; s=0.f;
  #pragma unroll
  for (int i=0;i<4;++i){
    float acc=B3v[i];
    #pragma unroll
    for (int o=0;o<16;++o) acc += W3[i][o]*a2g[o];
    a3[i]=acc; s+=acc;
  }
  m = s*0.25f; s2=0.f;
  #pragma unroll
  for (int i=0;i<4;++i){ float d=a3[i]-m; s2+=d*d; }
  rs = rsqrtf(s2*0.25f+1e-5f);
  float z = b4d;
  #pragma unroll
  for (int i=0;i<4;++i) z += W4d[i]*gelu_f((a3[i]-m)*rs*G3v[i]+T3v[i]);
  Outp[j0_global + jl] = 1.f/(1.f+expf(-z));
}

extern "C" void kernel_launch(void* const* d_in, const int* in_sizes, int n_in,
                              void* d_out, int out_size, void* d_ws, size_t ws_size,
                              hipStream_t stream)
{
  const float* gtok  = (const float*)d_in[0];
  const float* x     = (const float*)d_in[1];
  const float* ws1_w = (const float*)d_in[2];
  const float* ws1_b = (const float*)d_in[3];
  const float* ws2_w = (const float*)d_in[4];
  const float* ws2_b = (const float*)d_in[5];
  const float* wc1_w = (const float*)d_in[6];
  const float* wc1_b = (const float*)d_in[7];
  const float* wc2_w = (const float*)d_in[8];
  const float* wc2_b = (const float*)d_in[9];
  const float* q_w   = (const float*)d_in[10];
  const float* q_b   = (const float*)d_in[11];
  const float* k_w   = (const float*)d_in[12];
  const float* v_w   = (const float*)d_in[14];
  const float* v_b   = (const float*)d_in[15];
  const float* merge_w = (const float*)d_in[16];
  const float* merge_b = (const float*)d_in[17];
  const float* m1_w  = (const float*)d_in[18];
  const float* m1_b  = (const float*)d_in[19];
  const float* m2_w  = (const float*)d_in[20];
  const float* m2_b  = (const float*)d_in[21];
  const float* n0_g  = (const float*)d_in[22];
  const float* n0_b  = (const float*)d_in[23];
  const float* n1_g  = (const float*)d_in[24];
  const float* n1_b  = (const float*)d_in[25];
  const float* g1_w  = (const float*)d_in[26];
  const float* g1_b  = (const float*)d_in[27];
  const float* gl1_g = (const float*)d_in[28];
  const float* gl1_b = (const float*)d_in[29];
  const float* g2_w  = (const float*)d_in[30];
  const float* g2_b  = (const float*)d_in[31];
  const float* gl2_g = (const float*)d_in[32];
  const float* gl2_b = (const float*)d_in[33];
  const float* g3_w  = (const float*)d_in[34];
  const float* g3_b  = (const float*)d_in[35];
  const float* gl3_g = (const float*)d_in[36];
  const float* gl3_b = (const float*)d_in[37];
  const float* g4_w  = (const float*)d_in[38];
  const float* g4_b  = (n_in > 39) ? (const float*)d_in[39] : nullptr;

  const int TOT = 65536;
  const size_t PRE_BYTES = (size_t)16 * PRE_STRIDE * 4;
  const size_t GT1_B = 65536, HID_B = 262144, GT2_B = 65536;
  const size_t DK_B = 32768, DV_B = 32768, V1L_B = 32768;
  const size_t WB1_B = (size_t)1024*1024*2;
  const size_t WB2_B = (size_t)512*1024*2;
  const size_t WG_B  = (size_t)64*1024*2;
  const size_t FIXED = PRE_BYTES + GT1_B + HID_B + GT2_B + DK_B + DV_B + V1L_B
                     + WB1_B + WB2_B + WG_B;
  // per-chunk: XYbT 2048C + T1bT 2048C + T2bT 1024C + bufG 128C = 5248C bytes
  int C = 65536;
  while (C > 4096 && FIXED + (size_t)5248*C > ws_size) C >>= 1;
  const int nch = TOT / C;

  char* wsb = (char*)d_ws;
  size_t off = 0;
  float* PRE = (float*)(wsb + off); off += PRE_BYTES;
  float* GT1 = (float*)(wsb + off); off += GT1_B;
  float* HID = (float*)(wsb + off); off += HID_B;
  float* GT2 = (float*)(wsb + off); off += GT2_B;
  float* DK  = (float*)(wsb + off); off += DK_B;
  float* DV  = (float*)(wsb + off); off += DV_B;
  float* V1L = (float*)(wsb + off); off += V1L_B;
  u16* Wb1   = (u16*)(wsb + off);   off += WB1_B;
  u16* Wb2   = (u16*)(wsb + off);   off += WB2_B;
  u16* Wg    = (u16*)(wsb + off);   off += WG_B;
  u16* XYbT  = (u16*)(wsb + off);   off += (size_t)2048*C;  // [C][1024] bf16
  u16* T1bT  = (u16*)(wsb + off);   off += (size_t)2048*C;  // [C][1024] bf16
  u16* T2bT  = (u16*)(wsb + off);   off += (size_t)1024*C;  // [C][512] bf16
  u16* bufG  = (u16*)(wsb + off);   off += (size_t)128*C;   // [C][64] bf16

  dim3 blk(256);
  hipLaunchKernelGGL(kcvt, dim3(512), blk, 0, stream, m1_w, Wb1, 1024*1024/8);
  hipLaunchKernelGGL(kcvt, dim3(256), blk, 0, stream, m2_w, Wb2, 512*1024/8);
  hipLaunchKernelGGL(kcvt_dup, dim3(256), blk, 0, stream, g1_w, Wg);
  hipLaunchKernelGGL(k0a_mlps, dim3(16,2), blk, 0, stream,
      gtok, ws1_w, ws1_b, ws2_w, ws2_b, GT1);
  hipLaunchKernelGGL(k0b_fc1, dim3(16,8), blk, 0, stream, GT1, wc1_w, wc1_b, HID);
  hipLaunchKernelGGL(k0c_fc2, dim3(16,2), blk, 0, stream, GT1, HID, wc2_w, wc2_b, GT2);
  hipLaunchKernelGGL(k0d_kv,  dim3(16,2), blk, 0, stream, GT2, k_w, v_w, v_b, DK, DV, V1L);
  hipLaunchKernelGGL(k0e_qpre, dim3(16,2), blk, 0, stream, DK, q_w, q_b, PRE);
  hipLaunchKernelGGL(k0f_mpre, dim3(16,2), blk, 0, stream, DV, V1L, merge_w, merge_b, PRE);

  for (int ch = 0; ch < nch; ++ch){
    const int j0 = ch * C;
    dim3 cols(C/256);
    // x->bf16 + attn + merge + LN(n0) in one pass over x -> XYbT
    hipLaunchKernelGGL(k1_fused, cols, blk, 0, stream,
        x, PRE, n0_g, n0_b, j0, XYbT);
    // t1 = gelu(m1 @ XY + b) -> T1bT  (M=1024, nbi=8)
    hipLaunchKernelGGL(mfma_gemm_t, dim3(8*(C/128)), blk, 0, stream,
        Wb1, m1_b, XYbT, 1024, 1024, T1bT, 1, 3);
    // t2 = m2 @ t1 + b -> T2bT       (M=512, nbi=4)
    hipLaunchKernelGGL(mfma_gemm_t, dim3(4*(C/128)), blk, 0, stream,
        Wb2, m2_b, T1bT, 1024, 512, T2bT, 0, 2);
    // LN(t2; n1) -> bf16, overwrite y-half of XYbT (x-half stays = x bf16)
    hipLaunchKernelGGL(k_lnT, dim3(C/4), blk, 0, stream, T2bT, n1_g, n1_b, XYbT);
    // g1raw = [g1_w|g1_w] @ [x; LN(t2)] + b  (residual folded into GEMM)
    hipLaunchKernelGGL(mfma_g64, dim3(C/256), blk, 0, stream, Wg, g1_b, XYbT, bufG);
    // head
    hipLaunchKernelGGL(k_head, cols, blk, 0, stream,
        bufG, gl1_g, gl1_b, g2_w, g2_b, gl2_g, gl2_b,
        g3_w, g3_b, gl3_g, gl3_b,
        g4_w, g4_b ? g4_b : g4_w, g4_b ? 1 : 0, (float*)d_out, j0);
  }
}

// Round 7
// 1156.377 us; speedup vs baseline: 1.1265x; 1.1265x over previous
//
#include <hip/hip_runtime.h>
#include <math.h>

typedef unsigned short u16;
typedef __attribute__((ext_vector_type(8))) short bfrag;   // 8 bf16 (4 VGPRs)
typedef __attribute__((ext_vector_type(4))) float f32x4;

__device__ __forceinline__ float gelu_f(float x){
  return 0.5f * x * (1.0f + erff(x * 0.70710678118654752440f));
}
__device__ __forceinline__ u16 f2bf(float f){
  union { float f; unsigned int i; } c; c.f = f;
  unsigned int i = c.i;
  return (u16)((i + 0x7FFFu + ((i >> 16) & 1u)) >> 16);
}
__device__ __forceinline__ float bf2f(u16 u){
  union { unsigned int i; float f; } c; c.i = ((unsigned int)u) << 16; return c.f;
}

struct F8 { float v[8]; };
__device__ __forceinline__ F8 load8f(const float* p){
  float4 a = *(const float4*)p; float4 b = *(const float4*)(p + 4);
  F8 r; r.v[0]=a.x; r.v[1]=a.y; r.v[2]=a.z; r.v[3]=a.w;
  r.v[4]=b.x; r.v[5]=b.y; r.v[6]=b.z; r.v[7]=b.w; return r;
}

#define PRE_STRIDE 4624

// ============ k0 phase A: mlp_s (2->256->2) + residual -> GT1 ==============
__global__ __launch_bounds__(256) void k0a_mlps(
    const float* __restrict__ gtok,
    const float* __restrict__ ws1_w, const float* __restrict__ ws1_b,
    const float* __restrict__ ws2_w, const float* __restrict__ ws2_b,
    float* __restrict__ GT1)
{
  __shared__ float sw1[256][2]; __shared__ float sb1[256];
  __shared__ float sw2[2][256];
  const int b = blockIdx.x;
  const int t = threadIdx.x;
  sw1[t][0] = ws1_w[2*t]; sw1[t][1] = ws1_w[2*t+1];
  sb1[t] = ws1_b[t];
  sw2[0][t] = ws2_w[t]; sw2[1][t] = ws2_w[256+t];
  __syncthreads();
  const int j = blockIdx.y*256 + t;
  const float a0 = gtok[b*1024 + 2*j], a1 = gtok[b*1024 + 2*j + 1];
  float s0 = ws2_b[0], s1 = ws2_b[1];
  #pragma unroll 4
  for (int o = 0; o < 256; ++o){
    float h = gelu_f(sw1[o][0]*a0 + sw1[o][1]*a1 + sb1[o]);
    s0 += sw2[0][o]*h; s1 += sw2[1][o]*h;
  }
  GT1[b*1024 + 2*j]     = a0 + s0;
  GT1[b*1024 + 2*j + 1] = a1 + s1;
}

// ============ k0 phase B: fc1 of mlp_c (512->2048) -> HID ==================
__global__ __launch_bounds__(256) void k0b_fc1(
    const float* __restrict__ GT1,
    const float* __restrict__ wc1_w, const float* __restrict__ wc1_b,
    float* __restrict__ HID)
{
  __shared__ float g[1024];
  const int b = blockIdx.x;
  const int t = threadIdx.x;
  for (int i = t; i < 1024; i += 256) g[i] = GT1[b*1024 + i];
  __syncthreads();
  const int o = blockIdx.y*256 + t;
  const float* wr = wc1_w + (size_t)o*512;
  float acc0 = wc1_b[o], acc1 = acc0;
  for (int d = 0; d < 512; d += 8){
    F8 w = load8f(wr + d);
    #pragma unroll
    for (int i = 0; i < 8; ++i){
      acc0 += w.v[i]*g[(d+i)*2];
      acc1 += w.v[i]*g[(d+i)*2+1];
    }
  }
  HID[b*4096 + o]        = gelu_f(acc0);
  HID[b*4096 + 2048 + o] = gelu_f(acc1);
}

// ============ k0 phase C: fc2 of mlp_c (2048->512) + residual -> GT2 =======
__global__ __launch_bounds__(256) void k0c_fc2(
    const float* __restrict__ GT1, const float* __restrict__ HID,
    const float* __restrict__ wc2_w, const float* __restrict__ wc2_b,
    float* __restrict__ GT2)
{
  __shared__ float h0[2048], h1[2048];
  const int b = blockIdx.x;
  const int t = threadIdx.x;
  for (int i = t; i < 2048; i += 256){
    h0[i] = HID[b*4096 + i]; h1[i] = HID[b*4096 + 2048 + i];
  }
  __syncthreads();
  const int d = blockIdx.y*256 + t;
  const float* wr = wc2_w + (size_t)d*2048;
  float acc0 = wc2_b[d], acc1 = acc0;
  for (int o = 0; o < 2048; o += 8){
    F8 w = load8f(wr + o);
    #pragma unroll
    for (int i = 0; i < 8; ++i){
      acc0 += w.v[i]*h0[o+i];
      acc1 += w.v[i]*h1[o+i];
    }
  }
  GT2[b*1024 + 2*d]     = GT1[b*1024 + 2*d]     + acc0;
  GT2[b*1024 + 2*d + 1] = GT1[b*1024 + 2*d + 1] + acc1;
}

// ============ k0 phase D: k,v -> dk, dv, v1l ================================
__global__ __launch_bounds__(256) void k0d_kv(
    const float* __restrict__ GT2,
    const float* __restrict__ k_w,
    const float* __restrict__ v_w, const float* __restrict__ v_b,
    float* __restrict__ DK, float* __restrict__ DV, float* __restrict__ V1L)
{
  __shared__ float g[1024];
  const int b = blockIdx.x;
  const int t = threadIdx.x;
  for (int i = t; i < 1024; i += 256) g[i] = GT2[b*1024 + i];
  __syncthreads();
  const int c = blockIdx.y*256 + t;
  const float* kr = k_w + (size_t)c*512;
  const float* vr = v_w + (size_t)c*512;
  float k0a=0.f,k1a=0.f,v0a=0.f,v1a=0.f;
  for (int d = 0; d < 512; d += 8){
    F8 kw = load8f(kr + d); F8 vw = load8f(vr + d);
    #pragma unroll
    for (int i = 0; i < 8; ++i){
      float g0 = g[(d+i)*2], g1 = g[(d+i)*2+1];
      k0a += kw.v[i]*g0; k1a += kw.v[i]*g1;
      v0a += vw.v[i]*g0; v1a += vw.v[i]*g1;
    }
  }
  DK[b*512 + c]  = k0a - k1a;
  DV[b*512 + c]  = v0a - v1a;
  V1L[b*512 + c] = v1a + v_b[c];
}

// ============ k0 phase E: wdiff + beta4 -> PRE ==============================
__global__ __launch_bounds__(256) void k0e_qpre(
    const float* __restrict__ DK,
    const float* __restrict__ q_w, const float* __restrict__ q_b,
    float* __restrict__ PRE)
{
  __shared__ float dkl[512];
  const int b = blockIdx.x;
  const int t = threadIdx.x;
  for (int i = t; i < 512; i += 256) dkl[i] = DK[b*512 + i];
  __syncthreads();
  const int i = blockIdx.y*256 + t;
  float w0=0.f,w1=0.f,w2=0.f,w3=0.f;
  for (int c = 0; c < 512; c += 4){
    w0 += dkl[c]  *q_w[(size_t)(c)  *512 + i];
    w1 += dkl[c+1]*q_w[(size_t)(c+1)*512 + i];
    w2 += dkl[c+2]*q_w[(size_t)(c+2)*512 + i];
    w3 += dkl[c+3]*q_w[(size_t)(c+3)*512 + i];
  }
  float* P = PRE + (size_t)b * PRE_STRIDE;
  P[0*512+i]=w0; P[1*512+i]=w1; P[2*512+i]=w2; P[3*512+i]=w3;
  if (blockIdx.y == 0 && t < 4){
    float bsum = 0.f;
    for (int c = t; c < 512; c += 4) bsum += dkl[c]*q_b[c];
    P[2048 + t] = bsum;
  }
}

// ============ k0 phase F: base + M -> PRE ===================================
__global__ __launch_bounds__(256) void k0f_mpre(
    const float* __restrict__ DV, const float* __restrict__ V1L,
    const float* __restrict__ merge_w, const float* __restrict__ merge_b,
    float* __restrict__ PRE)
{
  __shared__ float dvl[512], v1ll[512];
  const int b = blockIdx.x;
  const int t = threadIdx.x;
  for (int i = t; i < 512; i += 256){
    dvl[i] = DV[b*512 + i]; v1ll[i] = V1L[b*512 + i];
  }
  __syncthreads();
  const int r = blockIdx.y*256 + t;
  const float* mw = merge_w + (size_t)r*512;
  float ab = merge_b[r];
  float mh[4] = {0.f,0.f,0.f,0.f};
  for (int c = 0; c < 512; c += 8){
    F8 w = load8f(mw + c);
    #pragma unroll
    for (int i = 0; i < 8; ++i){
      ab += w.v[i]*v1ll[c+i];
      mh[i&3] += w.v[i]*dvl[c+i];
    }
  }
  float* P = PRE + (size_t)b * PRE_STRIDE;
  P[2064 + r] = ab;
  *(float4*)&P[2576 + r*4] = make_float4(mh[0],mh[1],mh[2],mh[3]);
}

// ---------------- convert fp32 -> bf16 (flat) ------------------------------
__global__ __launch_bounds__(256) void kcvt(const float* __restrict__ s,
                                            u16* __restrict__ d, int n8)
{
  int g = blockIdx.x*256 + threadIdx.x;
  if (g >= n8) return;
  F8 v = load8f(s + (size_t)g*8);
  u16 o[8];
  #pragma unroll
  for (int i=0;i<8;++i) o[i] = f2bf(v.v[i]);
  *(uint4*)(d + (size_t)g*8) = *(uint4*)o;
}

// ------- build Wg64 [64][1024] = [g1_w | g1_w] bf16 ------------------------
__global__ __launch_bounds__(256) void kcvt_dup(const float* __restrict__ g1w,
                                                u16* __restrict__ out)
{
  int idx = blockIdx.x*256 + threadIdx.x;      // 65536 total
  int r = idx >> 10, k = idx & 1023;
  out[idx] = f2bf(g1w[r*512 + (k & 511)]);
}

// ---- K1: one pass over x: XYbT[j][0..511]=x bf16, [512..1023]=attn+LN(n0) --
__global__ __launch_bounds__(256) void k1_fused(
    const float* __restrict__ x, const float* __restrict__ PRE,
    const float* __restrict__ n0_g, const float* __restrict__ n0_b,
    int j0_global, u16* __restrict__ XYbT)
{
  __shared__ float wd[4][512];
  __shared__ float bs[512];
  __shared__ float Mm[512][4];
  __shared__ float gam[512], bet[512];
  __shared__ float beta4[4];
  const int tid = threadIdx.x;
  const int jl = blockIdx.x*256 + tid;
  const int jg = j0_global + jl;
  const int b = jg >> 12, n = jg & 4095;
  const float* P = PRE + (size_t)b * PRE_STRIDE;
  for (int i = tid; i < 2048; i += 256) wd[i>>9][i&511] = P[i];
  if (tid < 4) beta4[tid] = P[2048 + tid];
  for (int i = tid; i < 512; i += 256){
    bs[i] = P[2064 + i]; gam[i] = n0_g[i]; bet[i] = n0_b[i];
  }
  for (int i = tid; i < 2048; i += 256) Mm[i>>2][i&3] = P[2576 + i];
  __syncthreads();
  const float* xc = x + (size_t)b*2097152 + n;
  u16* col = XYbT + (size_t)jl*1024;
  float l0=beta4[0], l1=beta4[1], l2=beta4[2], l3=beta4[3];
  for (int i0 = 0; i0 < 512; i0 += 8){
    u16 ob[8];
    #pragma unroll
    for (int m = 0; m < 8; ++m){
      float xv = xc[(size_t)(i0+m)*4096];
      ob[m] = f2bf(xv);
      l0 += wd[0][i0+m]*xv; l1 += wd[1][i0+m]*xv;
      l2 += wd[2][i0+m]*xv; l3 += wd[3][i0+m]*xv;
    }
    *(uint4*)&col[i0] = *(uint4*)ob;
  }
  const float sc = 0.0883883476483184405f;
  float p0 = 1.f/(1.f+expf(-sc*l0));
  float p1 = 1.f/(1.f+expf(-sc*l1));
  float p2 = 1.f/(1.f+expf(-sc*l2));
  float p3 = 1.f/(1.f+expf(-sc*l3));
  float s=0.f, s2=0.f;
  for (int c = 0; c < 512; ++c){
    float m = bs[c] + Mm[c][0]*p0 + Mm[c][1]*p1 + Mm[c][2]*p2 + Mm[c][3]*p3;
    s += m; s2 += m*m;
  }
  float mean = s*(1.f/512.f);
  float rs = rsqrtf(s2*(1.f/512.f) - mean*mean + 1e-5f);
  for (int c0 = 0; c0 < 512; c0 += 8){
    u16 ob[8];
    #pragma unroll
    for (int m = 0; m < 8; ++m){
      int c = c0 + m;
      float v = bs[c] + Mm[c][0]*p0 + Mm[c][1]*p1 + Mm[c][2]*p2 + Mm[c][3]*p3;
      ob[m] = f2bf((v - mean)*rs*gam[c] + bet[c]);
    }
    *(uint4*)&col[512 + c0] = *(uint4*)ob;
  }
}

// --------- MFMA GEMM, register-staged pipelined, LDS double-buffered -------
// Out[C][M] bf16 = act(Wb @ XT^T + bias). Wb [M][K]; XT [C][1024].
// 128x128 tile, BK=32. Global loads go to VGPRs (no vmcnt drain at barrier),
// ds_write into alternating LDS halves -> 1 barrier/iter, latency hidden.
__global__ __launch_bounds__(256) void mfma_gemm_p(
    const u16* __restrict__ Wb, const float* __restrict__ bias,
    const u16* __restrict__ XT, int K, int M,
    u16* __restrict__ Out, int do_gelu, int log2nbi)
{
  __shared__ __align__(16) u16 SH[16384];   // 32 KB: [buf][A 4096 | B 4096]
  const int tid = threadIdx.x;
  const int lane = tid & 63;
  const int wv = __builtin_amdgcn_readfirstlane(tid >> 6);
  const int id = blockIdx.x;
  const int bi = (id >> 3) & ((1 << log2nbi) - 1);
  const int bj = (id & 7) + 8 * (id >> (3 + log2nbi));
  const int roff = (wv >> 1) * 64;
  const int noff = (wv & 1) * 64;
  const int lm = lane & 15, quad = lane >> 4;

  f32x4 acc[4][4];
  #pragma unroll
  for (int i=0;i<4;++i){
    #pragma unroll
    for (int j=0;j<4;++j) acc[i][j] = (f32x4){0.f,0.f,0.f,0.f};
  }
  // staging map: thread -> row tid>>1 (0..127), 32B chunk (tid&1)
  const int srow = tid >> 1;
  const int skc  = (tid & 1) * 16;
  const u16* aG = Wb + (size_t)(bi*128 + srow)*K + skc;
  const u16* bG = XT + (size_t)(bj*128 + srow)*1024 + skc;
  const int sIdx = srow*32 + skc;

  uint4 ra0 = *(const uint4*)(aG);
  uint4 ra1 = *(const uint4*)(aG + 8);
  uint4 rb0 = *(const uint4*)(bG);
  uint4 rb1 = *(const uint4*)(bG + 8);

  int buf = 0;
  for (int k0 = 0; k0 < K; k0 += 32){
    u16* A = SH + buf*8192;
    u16* B = A + 4096;
    *(uint4*)(A + sIdx)     = ra0;
    *(uint4*)(A + sIdx + 8) = ra1;
    *(uint4*)(B + sIdx)     = rb0;
    *(uint4*)(B + sIdx + 8) = rb1;
    if (k0 + 32 < K){                 // prefetch next tile into regs
      ra0 = *(const uint4*)(aG + k0 + 32);
      ra1 = *(const uint4*)(aG + k0 + 40);
      rb0 = *(const uint4*)(bG + k0 + 32);
      rb1 = *(const uint4*)(bG + k0 + 40);
    }
    __syncthreads();
    bfrag av[4], bv[4];
    #pragma unroll
    for (int i=0;i<4;++i)
      av[i] = *(const bfrag*)&A[(roff + 16*i + lm)*32 + quad*8];
    #pragma unroll
    for (int j=0;j<4;++j)
      bv[j] = *(const bfrag*)&B[(noff + 16*j + lm)*32 + quad*8];
    #pragma unroll
    for (int i=0;i<4;++i){
      #pragma unroll
      for (int j=0;j<4;++j)
        acc[i][j] = __builtin_amdgcn_mfma_f32_16x16x32_bf16(av[i], bv[j], acc[i][j], 0,0,0);
    }
    buf ^= 1;
  }
  __syncthreads();
  // coalesced epilogue via LDS transpose (reuse SH): 2 passes of 64 cols
  u16* Tt = SH;                       // needs 64*136 = 8704 u16 <= 16384
  #pragma unroll
  for (int p = 0; p < 2; ++p){
    if ((wv & 1) == p){
      #pragma unroll
      for (int i=0;i<4;++i){
        float4 bb = *(const float4*)&bias[bi*128 + roff + 16*i + quad*4];
        float b4[4] = {bb.x,bb.y,bb.z,bb.w};
        #pragma unroll
        for (int j=0;j<4;++j){
          int colr = 16*j + lm;
          #pragma unroll
          for (int s2=0;s2<2;++s2){
            float v0 = acc[i][j][2*s2]   + b4[2*s2];
            float v1 = acc[i][j][2*s2+1] + b4[2*s2+1];
            if (do_gelu){ v0 = gelu_f(v0); v1 = gelu_f(v1); }
            unsigned int dw = (unsigned int)f2bf(v0) | ((unsigned int)f2bf(v1) << 16);
            *(unsigned int*)&Tt[colr*136 + roff + 16*i + quad*4 + 2*s2] = dw;
          }
        }
      }
    }
    __syncthreads();
    {
      int c = tid >> 2, q = tid & 3;
      u16* dst = Out + (size_t)(bj*128 + p*64 + c)*M + bi*128 + q*32;
      const u16* src = &Tt[c*136 + q*32];
      #pragma unroll
      for (int m=0;m<2;++m){
        *(uint4*)(dst + m*8)      = *(const uint4*)(src + m*8);
        *(uint4*)(dst + 16 + m*8) = *(const uint4*)(src + 16 + m*8);
      }
    }
    __syncthreads();
  }
}

// --------- MFMA GEMM 64-row (g1): Out[C][64] bf16 = Wg @ XT^T + b ----------
// Register-staged + LDS double-buffered like mfma_gemm_p. 64x256 tile.
__global__ __launch_bounds__(256) void mfma_g64(
    const u16* __restrict__ Wg, const float* __restrict__ bias,
    const u16* __restrict__ XT, u16* __restrict__ Out)
{
  __shared__ __align__(16) u16 SH[20480];  // 40KB: [buf][A 2048 | B 8192]
  const int tid = threadIdx.x;
  const int lane = tid & 63;
  const int wv = __builtin_amdgcn_readfirstlane(tid >> 6);
  const int bj = blockIdx.x;
  const int lm = lane & 15, quad = lane >> 4;

  f32x4 acc[4][4];
  #pragma unroll
  for (int i=0;i<4;++i){
    #pragma unroll
    for (int j=0;j<4;++j) acc[i][j] = (f32x4){0.f,0.f,0.f,0.f};
  }
  const int srow = tid >> 2;           // 0..63
  const int skc  = (tid & 3) * 8;      // 16B chunk
  const u16* aG = Wg + (size_t)srow*1024 + skc;
  const u16* bG = XT + (size_t)(bj*256 + srow)*1024 + skc;
  const int sIdx = srow*32 + skc;

  uint4 ra = *(const uint4*)(aG);
  uint4 rb[4];
  #pragma unroll
  for (int s=0;s<4;++s) rb[s] = *(const uint4*)(bG + (size_t)s*64*1024);

  int buf = 0;
  for (int k0 = 0; k0 < 1024; k0 += 32){
    u16* A = SH + buf*10240;
    u16* B = A + 2048;
    *(uint4*)(A + sIdx) = ra;
    #pragma unroll
    for (int s=0;s<4;++s) *(uint4*)(B + s*2048 + sIdx) = rb[s];
    if (k0 + 32 < 1024){
      ra = *(const uint4*)(aG + k0 + 32);
      #pragma unroll
      for (int s=0;s<4;++s) rb[s] = *(const uint4*)(bG + (size_t)s*64*1024 + k0 + 32);
    }
    __syncthreads();
    bfrag av[4], bv[4];
    #pragma unroll
    for (int i=0;i<4;++i)
      av[i] = *(const bfrag*)&A[(16*i + lm)*32 + quad*8];
    #pragma unroll
    for (int j=0;j<4;++j)
      bv[j] = *(const bfrag*)&B[(wv*64 + 16*j + lm)*32 + quad*8];
    #pragma unroll
    for (int i=0;i<4;++i){
      #pragma unroll
      for (int j=0;j<4;++j)
        acc[i][j] = __builtin_amdgcn_mfma_f32_16x16x32_bf16(av[i], bv[j], acc[i][j], 0,0,0);
    }
    buf ^= 1;
  }
  __syncthreads();
  // epilogue: stage 256x64 tile (stride 72) in SH, then coalesced store
  u16* Tg = SH;                        // needs 256*72 = 18432 u16 <= 20480
  #pragma unroll
  for (int i=0;i<4;++i){
    float4 bb = *(const float4*)&bias[16*i + quad*4];
    float b4[4] = {bb.x,bb.y,bb.z,bb.w};
    #pragma unroll
    for (int j=0;j<4;++j){
      int col = wv*64 + 16*j + lm;
      #pragma unroll
      for (int s2=0;s2<2;++s2){
        float v0 = acc[i][j][2*s2]   + b4[2*s2];
        float v1 = acc[i][j][2*s2+1] + b4[2*s2+1];
        unsigned int dw = (unsigned int)f2bf(v0) | ((unsigned int)f2bf(v1) << 16);
        *(unsigned int*)&Tg[col*72 + 16*i + quad*4 + 2*s2] = dw;
      }
    }
  }
  __syncthreads();
  {
    u16* dst = Out + (size_t)(bj*256 + tid)*64;
    const u16* src = &Tg[tid*72];
    #pragma unroll
    for (int m=0;m<8;++m)
      *(uint4*)(dst + m*8) = *(const uint4*)(src + m*8);
  }
}

// ---- LN over 512 ch, wave-per-column; bf16 in, bf16 out into XYbT y-half --
__global__ __launch_bounds__(256) void k_lnT(
    const u16* __restrict__ t2T,
    const float* __restrict__ gamma, const float* __restrict__ beta,
    u16* __restrict__ XYbT)
{
  __shared__ float gam[512], bet[512];
  const int tid = threadIdx.x;
  for (int c = tid; c < 512; c += 256){ gam[c]=gamma[c]; bet[c]=beta[c]; }
  __syncthreads();
  const int lane = tid & 63, wv = tid >> 6;
  const int j = blockIdx.x*4 + wv;
  uint4 w = *(const uint4*)(t2T + (size_t)j*512 + lane*8);
  const u16* wp = (const u16*)&w;
  float vv[8];
  #pragma unroll
  for (int m=0;m<8;++m) vv[m] = bf2f(wp[m]);
  float s = 0.f, s2 = 0.f;
  #pragma unroll
  for (int m=0;m<8;++m){ s += vv[m]; s2 += vv[m]*vv[m]; }
  #pragma unroll
  for (int off = 32; off; off >>= 1){
    s  += __shfl_xor(s,  off, 64);
    s2 += __shfl_xor(s2, off, 64);
  }
  float mean = s*(1.f/512.f);
  float rs = rsqrtf(s2*(1.f/512.f) - mean*mean + 1e-5f);
  u16 ob[8];
  #pragma unroll
  for (int m=0;m<8;++m){
    int c = lane*8 + m;
    ob[m] = f2bf((vv[m]-mean)*rs*gam[c] + bet[c]);
  }
  *(uint4*)&XYbT[(size_t)j*1024 + 512 + lane*8] = *(uint4*)ob;
}

// ------- head: LN64+gelu -> 16 -> 4 -> 2, softmax ch0; G is [C][64] bf16 ---
__global__ __launch_bounds__(256) void k_head(
    const u16* __restrict__ G,
    const float* __restrict__ gl1_g, const float* __restrict__ gl1_b,
    const float* __restrict__ g2_w, const float* __restrict__ g2_b,
    const float* __restrict__ gl2_g, const float* __restrict__ gl2_b,
    const float* __restrict__ g3_w, const float* __restrict__ g3_b,
    const float* __restrict__ gl3_g, const float* __restrict__ gl3_b,
    const float* __restrict__ g4_w, const float* __restrict__ g4_b, int has_g4b,
    float* __restrict__ Outp, int j0_global)
{
  __shared__ float L1g[64], L1b[64];
  __shared__ float W2[16][64], B2v[16], G2v[16], T2v[16];
  __shared__ float W3[4][16], B3v[4], G3v[4], T3v[4];
  __shared__ float W4d[4]; __shared__ float b4d;
  const int tid = threadIdx.x;
  if (tid < 64){ L1g[tid]=gl1_g[tid]; L1b[tid]=gl1_b[tid]; }
  for (int i = tid; i < 1024; i += 256) W2[i>>6][i&63] = g2_w[i];
  if (tid < 16){ B2v[tid]=g2_b[tid]; G2v[tid]=gl2_g[tid]; T2v[tid]=gl2_b[tid]; }
  if (tid < 64) W3[tid>>4][tid&15] = g3_w[tid];
  if (tid < 4){ B3v[tid]=g3_b[tid]; G3v[tid]=gl3_g[tid]; T3v[tid]=gl3_b[tid];
                W4d[tid] = g4_w[tid] - g4_w[4+tid]; }
  if (tid == 0) b4d = has_g4b ? (g4_b[0] - g4_b[1]) : 0.f;
  __syncthreads();
  const int jl = blockIdx.x*256 + tid;
  const u16* gc = G + (size_t)jl*64;
  float a1[64]; float s=0.f;
  #pragma unroll
  for (int c0=0;c0<64;c0+=8){
    uint4 w = *(const uint4*)(gc + c0);
    const u16* wp = (const u16*)&w;
    #pragma unroll
    for (int m=0;m<8;++m){ a1[c0+m] = bf2f(wp[m]); s += a1[c0+m]; }
  }
  float m = s*(1.f/64.f); float s2=0.f;
  #pragma unroll
  for (int c=0;c<64;++c){ float d=a1[c]-m; s2+=d*d; }
  float rs = rsqrtf(s2*(1.f/64.f)+1e-5f);
  #pragma unroll
  for (int c=0;c<64;++c) a1[c] = gelu_f((a1[c]-m)*rs*L1g[c]+L1b[c]);

  float a2[16]; s=0.f;
  #pragma unroll
  for (int i=0;i<16;++i){
    float acc = B2v[i];
    #pragma unroll
    for (int o=0;o<64;++o) acc += W2[i][o]*a1[o];
    a2[i]=acc; s+=acc;
  }
  m = s*(1.f/16.f); s2=0.f;
  #pragma unroll
  for (int i=0;i<16;++i){ float d=a2[i]-m; s2+=d*d; }
  rs = rsqrtf(s2*(1.f/16.f)+1e-5f);
  float a2g[16];
  #pragma unroll
  for (int i=0;i<16;++i) a2g[i] = gelu_f((a2[i]-m)*rs*G2v[i]+T2v[i]);

  float a3[4]; s=0.f;
  #pragma unroll
  for (int i=0;i<4;++i){
    float acc=B3v[i];
    #pragma unroll
    for (int o=0;o<16;++o) acc += W3[i][o]*a2g[o];
    a3[i]=acc; s+=acc;
  }
  m = s*0.25f; s2=0.f;
  #pragma unroll
  for (int i=0;i<4;++i){ float d=a3[i]-m; s2+=d*d; }
  rs = rsqrtf(s2*0.25f+1e-5f);
  float z = b4d;
  #pragma unroll
  for (int i=0;i<4;++i) z += W4d[i]*gelu_f((a3[i]-m)*rs*G3v[i]+T3v[i]);
  Outp[j0_global + jl] = 1.f/(1.f+expf(-z));
}

extern "C" void kernel_launch(void* const* d_in, const int* in_sizes, int n_in,
                              void* d_out, int out_size, void* d_ws, size_t ws_size,
                              hipStream_t stream)
{
  const float* gtok  = (const float*)d_in[0];
  const float* x     = (const float*)d_in[1];
  const float* ws1_w = (const float*)d_in[2];
  const float* ws1_b = (const float*)d_in[3];
  const float* ws2_w = (const float*)d_in[4];
  const float* ws2_b = (const float*)d_in[5];
  const float* wc1_w = (const float*)d_in[6];
  const float* wc1_b = (const float*)d_in[7];
  const float* wc2_w = (const float*)d_in[8];
  const float* wc2_b = (const float*)d_in[9];
  const float* q_w   = (const float*)d_in[10];
  const float* q_b   = (const float*)d_in[11];
  const float* k_w   = (const float*)d_in[12];
  const float* v_w   = (const float*)d_in[14];
  const float* v_b   = (const float*)d_in[15];
  const float* merge_w = (const float*)d_in[16];
  const float* merge_b = (const float*)d_in[17];
  const float* m1_w  = (const float*)d_in[18];
  const float* m1_b  = (const float*)d_in[19];
  const float* m2_w  = (const float*)d_in[20];
  const float* m2_b  = (const float*)d_in[21];
  const float* n0_g  = (const float*)d_in[22];
  const float* n0_b  = (const float*)d_in[23];
  const float* n1_g  = (const float*)d_in[24];
  const float* n1_b  = (const float*)d_in[25];
  const float* g1_w  = (const float*)d_in[26];
  const float* g1_b  = (const float*)d_in[27];
  const float* gl1_g = (const float*)d_in[28];
  const float* gl1_b = (const float*)d_in[29];
  const float* g2_w  = (const float*)d_in[30];
  const float* g2_b  = (const float*)d_in[31];
  const float* gl2_g = (const float*)d_in[32];
  const float* gl2_b = (const float*)d_in[33];
  const float* g3_w  = (const float*)d_in[34];
  const float* g3_b  = (const float*)d_in[35];
  const float* gl3_g = (const float*)d_in[36];
  const float* gl3_b = (const float*)d_in[37];
  const float* g4_w  = (const float*)d_in[38];
  const float* g4_b  = (n_in > 39) ? (const float*)d_in[39] : nullptr;

  const int TOT = 65536;
  const size_t PRE_BYTES = (size_t)16 * PRE_STRIDE * 4;
  const size_t GT1_B = 65536, HID_B = 262144, GT2_B = 65536;
  const size_t DK_B = 32768, DV_B = 32768, V1L_B = 32768;
  const size_t WB1_B = (size_t)1024*1024*2;
  const size_t WB2_B = (size_t)512*1024*2;
  const size_t WG_B  = (size_t)64*1024*2;
  const size_t FIXED = PRE_BYTES + GT1_B + HID_B + GT2_B + DK_B + DV_B + V1L_B
                     + WB1_B + WB2_B + WG_B;
  // per-chunk: XYbT 2048C + T1bT 2048C + T2bT 1024C + bufG 128C = 5248C bytes
  int C = 65536;
  while (C > 4096 && FIXED + (size_t)5248*C > ws_size) C >>= 1;
  const int nch = TOT / C;

  char* wsb = (char*)d_ws;
  size_t off = 0;
  float* PRE = (float*)(wsb + off); off += PRE_BYTES;
  float* GT1 = (float*)(wsb + off); off += GT1_B;
  float* HID = (float*)(wsb + off); off += HID_B;
  float* GT2 = (float*)(wsb + off); off += GT2_B;
  float* DK  = (float*)(wsb + off); off += DK_B;
  float* DV  = (float*)(wsb + off); off += DV_B;
  float* V1L = (float*)(wsb + off); off += V1L_B;
  u16* Wb1   = (u16*)(wsb + off);   off += WB1_B;
  u16* Wb2   = (u16*)(wsb + off);   off += WB2_B;
  u16* Wg    = (u16*)(wsb + off);   off += WG_B;
  u16* XYbT  = (u16*)(wsb + off);   off += (size_t)2048*C;  // [C][1024] bf16
  u16* T1bT  = (u16*)(wsb + off);   off += (size_t)2048*C;  // [C][1024] bf16
  u16* T2bT  = (u16*)(wsb + off);   off += (size_t)1024*C;  // [C][512] bf16
  u16* bufG  = (u16*)(wsb + off);   off += (size_t)128*C;   // [C][64] bf16

  dim3 blk(256);
  hipLaunchKernelGGL(kcvt, dim3(512), blk, 0, stream, m1_w, Wb1, 1024*1024/8);
  hipLaunchKernelGGL(kcvt, dim3(256), blk, 0, stream, m2_w, Wb2, 512*1024/8);
  hipLaunchKernelGGL(kcvt_dup, dim3(256), blk, 0, stream, g1_w, Wg);
  hipLaunchKernelGGL(k0a_mlps, dim3(16,2), blk, 0, stream,
      gtok, ws1_w, ws1_b, ws2_w, ws2_b, GT1);
  hipLaunchKernelGGL(k0b_fc1, dim3(16,8), blk, 0, stream, GT1, wc1_w, wc1_b, HID);
  hipLaunchKernelGGL(k0c_fc2, dim3(16,2), blk, 0, stream, GT1, HID, wc2_w, wc2_b, GT2);
  hipLaunchKernelGGL(k0d_kv,  dim3(16,2), blk, 0, stream, GT2, k_w, v_w, v_b, DK, DV, V1L);
  hipLaunchKernelGGL(k0e_qpre, dim3(16,2), blk, 0, stream, DK, q_w, q_b, PRE);
  hipLaunchKernelGGL(k0f_mpre, dim3(16,2), blk, 0, stream, DV, V1L, merge_w, merge_b, PRE);

  for (int ch = 0; ch < nch; ++ch){
    const int j0 = ch * C;
    dim3 cols(C/256);
    // x->bf16 + attn + merge + LN(n0) in one pass over x -> XYbT
    hipLaunchKernelGGL(k1_fused, cols, blk, 0, stream,
        x, PRE, n0_g, n0_b, j0, XYbT);
    // t1 = gelu(m1 @ XY + b) -> T1bT  (M=1024, nbi=8)
    hipLaunchKernelGGL(mfma_gemm_p, dim3(8*(C/128)), blk, 0, stream,
        Wb1, m1_b, XYbT, 1024, 1024, T1bT, 1, 3);
    // t2 = m2 @ t1 + b -> T2bT       (M=512, nbi=4)
    hipLaunchKernelGGL(mfma_gemm_p, dim3(4*(C/128)), blk, 0, stream,
        Wb2, m2_b, T1bT, 1024, 512, T2bT, 0, 2);
    // LN(t2; n1) -> bf16, overwrite y-half of XYbT (x-half stays = x bf16)
    hipLaunchKernelGGL(k_lnT, dim3(C/4), blk, 0, stream, T2bT, n1_g, n1_b, XYbT);
    // g1raw = [g1_w|g1_w] @ [x; LN(t2)] + b  (residual folded into GEMM)
    hipLaunchKernelGGL(mfma_g64, dim3(C/256), blk, 0, stream, Wg, g1_b, XYbT, bufG);
    // head
    hipLaunchKernelGGL(k_head, cols, blk, 0, stream,
        bufG, gl1_g, gl1_b, g2_w, g2_b, gl2_g, gl2_b,
        g3_w, g3_b, gl3_g, gl3_b,
        g4_w, g4_b ? g4_b : g4_w, g4_b ? 1 : 0, (float*)d_out, j0);
  }
}